// Round 1
// baseline (454.108 us; speedup 1.0000x reference)
//
#include <hip/hip_runtime.h>
#include <math.h>

#define CF 256
#define HID 170
#define NE 8
#define NTOK 512
#define K1 2304      // 256*9
#define K2P 1536     // 170*9 = 1530 padded to 1536
#define CAPACITY 161

__device__ __forceinline__ float silu_f(float x) { return x / (1.0f + expf(-x)); }

// Cubic B-spline bases on uniform grid g(j) = (j-3)*0.4 - 1, j=0..11 -> 8 bases
__device__ __forceinline__ void bspline8(float x, float bs[8]) {
    float b[11];
#pragma unroll
    for (int j = 0; j < 11; ++j) {
        float g0 = (float)(j - 3) * 0.4f - 1.0f;
        float g1 = (float)(j - 2) * 0.4f - 1.0f;
        b[j] = (x >= g0 && x < g1) ? 1.0f : 0.0f;
    }
#pragma unroll
    for (int k = 1; k <= 3; ++k) {
#pragma unroll
        for (int j = 0; j < 11 - 3; ++j) { // max iterations; guard below
            if (j < 11 - k) {
                float gj   = (float)(j - 3) * 0.4f - 1.0f;
                float gjk  = (float)(j - 3 + k) * 0.4f - 1.0f;
                float gj1  = (float)(j - 2) * 0.4f - 1.0f;
                float gjk1 = (float)(j - 2 + k) * 0.4f - 1.0f;
                b[j] = (x - gj) / (gjk - gj) * b[j] + (gjk1 - x) / (gjk1 - gj1) * b[j + 1];
            }
        }
        // handle remaining j for k<3 (j in [8, 11-k))
        if (k == 1) {
            for (int j = 8; j < 10; ++j) {
                float gj   = (float)(j - 3) * 0.4f - 1.0f;
                float gjk  = (float)(j - 3 + 1) * 0.4f - 1.0f;
                float gj1  = (float)(j - 2) * 0.4f - 1.0f;
                float gjk1 = (float)(j - 2 + 1) * 0.4f - 1.0f;
                b[j] = (x - gj) / (gjk - gj) * b[j] + (gjk1 - x) / (gjk1 - gj1) * b[j + 1];
            }
        } else if (k == 2) {
            int j = 8;
            float gj   = (float)(j - 3) * 0.4f - 1.0f;
            float gjk  = (float)(j - 3 + 2) * 0.4f - 1.0f;
            float gj1  = (float)(j - 2) * 0.4f - 1.0f;
            float gjk1 = (float)(j - 2 + 2) * 0.4f - 1.0f;
            b[j] = (x - gj) / (gjk - gj) * b[j] + (gjk1 - x) / (gjk1 - gj1) * b[j + 1];
        }
    }
#pragma unroll
    for (int c = 0; c < 8; ++c) bs[c] = b[c];
}

// ---- 1. pooling: fused (concat) volume -> vec (512,256) --------------------
__global__ __launch_bounds__(256) void pool_kernel(const float* __restrict__ fpn,
                                                   const float* __restrict__ seg,
                                                   float* __restrict__ vec) {
    int c = blockIdx.x, b = blockIdx.y, tid = threadIdx.x;
    const float* src = (c < 254) ? fpn + (size_t)(b * 254 + c) * 32768
                                 : seg + (size_t)(b * 2 + (c - 254)) * 32768;
    const float4* s4 = (const float4*)src;
    float s[4] = {0.f, 0.f, 0.f, 0.f};
#pragma unroll
    for (int it = 0; it < 32; ++it) {
        float4 v = s4[it * 256 + tid];
        s[it >> 3] += v.x + v.y + v.z + v.w;
    }
    __shared__ float acc[64];
    if (tid < 64) acc[tid] = 0.0f;
    __syncthreads();
    int bh = tid >> 6, bw = (tid & 7) >> 1;
#pragma unroll
    for (int bd = 0; bd < 4; ++bd) atomicAdd(&acc[bd * 16 + bh * 4 + bw], s[bd]);
    __syncthreads();
    if (tid < 64) vec[(size_t)(b * 64 + tid) * CF + c] = acc[tid] * (1.0f / 512.0f);
}

// ---- 2. router: layernorm + scores + top2 + capacity -----------------------
__global__ __launch_bounds__(512) void router_kernel(const float* __restrict__ vec,
                                                     const float* __restrict__ lnw,
                                                     const float* __restrict__ lnb,
                                                     const float* __restrict__ rw,
                                                     const float* __restrict__ rb,
                                                     float* __restrict__ xnorm,
                                                     float* __restrict__ cw,
                                                     float* __restrict__ conf) {
    int n = threadIdx.x;
    const float* row = vec + (size_t)n * CF;
    float s = 0.f, ss = 0.f;
    for (int i = 0; i < CF; ++i) { float v = row[i]; s += v; ss += v * v; }
    float mu = s * (1.0f / CF);
    float var = ss * (1.0f / CF) - mu * mu;
    float rs = rsqrtf(var + 1e-5f);
    float acc[NE];
#pragma unroll
    for (int e = 0; e < NE; ++e) acc[e] = 0.f;
    for (int i = 0; i < CF; ++i) {
        float xv = (row[i] - mu) * rs * lnw[i] + lnb[i];
        xnorm[(size_t)n * CF + i] = xv;
#pragma unroll
        for (int e = 0; e < NE; ++e) acc[e] += xv * rw[e * CF + i];
    }
    float m1 = -1e30f, m2 = -1e30f; int i1 = 0, i2 = 0;
#pragma unroll
    for (int e = 0; e < NE; ++e) {
        float sc = acc[e] + rb[e];
        if (sc > m1) { m2 = m1; i2 = i1; m1 = sc; i1 = e; }
        else if (sc > m2) { m2 = sc; i2 = e; }
    }
    conf[n] = m1;
    float ew = expf(m2 - m1);
    float w1 = 1.0f / (1.0f + ew), w2 = ew / (1.0f + ew);
    __shared__ int   ti[NTOK][2];
    __shared__ float tw[NTOK][2];
    ti[n][0] = i1; ti[n][1] = i2; tw[n][0] = w1; tw[n][1] = w2;
    __syncthreads();
    if (n < NE) {
        int e = n, cnt = 0;
        for (int t = 0; t < NTOK; ++t) {
            int h0 = (ti[t][0] == e), h1 = (ti[t][1] == e);
            float wv = 0.f;
            if (h0 | h1) {
                cnt++;
                if (cnt <= CAPACITY) wv = h0 ? tw[t][0] : tw[t][1];
            }
            cw[e * NTOK + t] = wv;
        }
    }
}

// ---- 3. build augmented activations / weights ------------------------------
__global__ __launch_bounds__(256) void buildA1_kernel(const float* __restrict__ xnorm,
                                                      float* __restrict__ A1) {
    int n = blockIdx.x, i = threadIdx.x;
    float x = xnorm[(size_t)n * CF + i];
    float* r = A1 + (size_t)n * K1;
    r[i] = silu_f(x);
    float bs[8]; bspline8(x, bs);
    float* sp = r + CF + i * 8;
#pragma unroll
    for (int c = 0; c < 8; ++c) sp[c] = bs[c];
}

__global__ __launch_bounds__(256) void buildW1_kernel(const float* __restrict__ bw1,
                                                      const float* __restrict__ sw1,
                                                      const float* __restrict__ sc1,
                                                      float* __restrict__ W1) {
    int o = blockIdx.x, e = blockIdx.y, i = threadIdx.x;
    size_t oi = (size_t)(e * HID + o) * CF + i;
    float* r = W1 + (size_t)(e * HID + o) * K1;
    r[i] = bw1[oi];
    float sc = sc1[oi];
    const float* sw = sw1 + oi * 8;
    float* sp = r + CF + i * 8;
#pragma unroll
    for (int c = 0; c < 8; ++c) sp[c] = sw[c] * sc;
}

__global__ __launch_bounds__(192) void buildW2_kernel(const float* __restrict__ bw2,
                                                      const float* __restrict__ sw2,
                                                      const float* __restrict__ sc2,
                                                      float* __restrict__ W2) {
    int o = blockIdx.x, e = blockIdx.y, t = threadIdx.x;
    float* r = W2 + (size_t)(e * CF + o) * K2P;
    if (t < HID) {
        size_t oi = (size_t)(e * CF + o) * HID + t;
        r[t] = bw2[oi];
        float sc = sc2[oi];
        const float* sw = sw2 + oi * 8;
        float* sp = r + HID + t * 8;
#pragma unroll
        for (int c = 0; c < 8; ++c) sp[c] = sw[c] * sc;
    } else if (t < HID + 6) {
        r[HID * 9 + (t - HID)] = 0.0f;
    }
}

__global__ __launch_bounds__(192) void buildA2_kernel(const float* __restrict__ H,
                                                      float* __restrict__ A2) {
    int n = blockIdx.x, e = blockIdx.y, t = threadIdx.x;
    float* r = A2 + (size_t)(e * NTOK + n) * K2P;
    if (t < HID) {
        float h = H[(size_t)(e * NTOK + n) * HID + t];
        r[t] = silu_f(h);
        float bs[8]; bspline8(h, bs);
        float* sp = r + HID + t * 8;
#pragma unroll
        for (int c = 0; c < 8; ++c) sp[c] = bs[c];
    } else if (t < HID + 6) {
        r[HID * 9 + (t - HID)] = 0.0f;
    }
}

// ---- 4. batched f32 GEMM: C[e] = A[e] (M,K) * B[e] (N,K)^T -----------------
__global__ __launch_bounds__(256) void gemm_nt_kernel(const float* __restrict__ A,
                                                      const float* __restrict__ B,
                                                      float* __restrict__ C,
                                                      int N, int K, int lda, int ldb, int ldc,
                                                      long sA, long sB, long sC, int act) {
    int e = blockIdx.z;
    A += (size_t)e * sA; B += (size_t)e * sB; C += (size_t)e * sC;
    int m0 = blockIdx.y * 64, n0 = blockIdx.x * 64;
    __shared__ float As[16][64];
    __shared__ float Bs[16][64];
    int tid = threadIdx.x;
    int lr = tid >> 2, lk = (tid & 3) * 4;
    int tx = tid & 15, ty = tid >> 4;
    float acc[4][4];
#pragma unroll
    for (int i = 0; i < 4; ++i)
#pragma unroll
        for (int j = 0; j < 4; ++j) acc[i][j] = 0.f;
    for (int k0 = 0; k0 < K; k0 += 16) {
        float4 a = *(const float4*)&A[(size_t)(m0 + lr) * lda + k0 + lk];
        float4 b = make_float4(0.f, 0.f, 0.f, 0.f);
        int br = n0 + lr;
        if (br < N) b = *(const float4*)&B[(size_t)br * ldb + k0 + lk];
        __syncthreads();
        As[lk + 0][lr] = a.x; As[lk + 1][lr] = a.y; As[lk + 2][lr] = a.z; As[lk + 3][lr] = a.w;
        Bs[lk + 0][lr] = b.x; Bs[lk + 1][lr] = b.y; Bs[lk + 2][lr] = b.z; Bs[lk + 3][lr] = b.w;
        __syncthreads();
#pragma unroll
        for (int k = 0; k < 16; ++k) {
            float4 av = *(const float4*)&As[k][tx * 4];
            float4 bv = *(const float4*)&Bs[k][ty * 4];
            float am[4] = {av.x, av.y, av.z, av.w};
            float bn[4] = {bv.x, bv.y, bv.z, bv.w};
#pragma unroll
            for (int i = 0; i < 4; ++i)
#pragma unroll
                for (int j = 0; j < 4; ++j) acc[i][j] = fmaf(am[i], bn[j], acc[i][j]);
        }
    }
#pragma unroll
    for (int i = 0; i < 4; ++i) {
        int m = m0 + tx * 4 + i;
#pragma unroll
        for (int j = 0; j < 4; ++j) {
            int nn = n0 + ty * 4 + j;
            if (nn < N) {
                float v = acc[i][j];
                if (act) v = 0.5f * v * (1.0f + erff(v * 0.70710678118654752f));
                C[(size_t)m * ldc + nn] = v;
            }
        }
    }
}

// ---- 5. combine experts ----------------------------------------------------
__global__ __launch_bounds__(256) void combine_kernel(const float* __restrict__ y,
                                                      const float* __restrict__ cw,
                                                      float* __restrict__ outc) {
    int n = blockIdx.x, c = threadIdx.x;
    float a = 0.f;
#pragma unroll
    for (int e = 0; e < NE; ++e)
        a += cw[e * NTOK + n] * y[((size_t)(e * NTOK + n)) * CF + c];
    outc[(size_t)n * CF + c] = a;
}

// ---- 6. classifier KAN (layernorm + kan_linear to 2 logits) ----------------
__global__ __launch_bounds__(256) void cls_kernel(const float* __restrict__ outc,
                                                  const float* __restrict__ lnw,
                                                  const float* __restrict__ lnb,
                                                  const float* __restrict__ cbw,
                                                  const float* __restrict__ csw,
                                                  const float* __restrict__ csc,
                                                  float* __restrict__ lblk) {
    int n = blockIdx.x, i = threadIdx.x;
    float v = outc[(size_t)n * CF + i];
    float s1 = v, s2 = v * v;
#pragma unroll
    for (int off = 32; off > 0; off >>= 1) {
        s1 += __shfl_xor(s1, off);
        s2 += __shfl_xor(s2, off);
    }
    __shared__ float rA[4], rB[4], rP0[4], rP1[4];
    int lane = i & 63, wid = i >> 6;
    if (lane == 0) { rA[wid] = s1; rB[wid] = s2; }
    __syncthreads();
    float tot1 = rA[0] + rA[1] + rA[2] + rA[3];
    float tot2 = rB[0] + rB[1] + rB[2] + rB[3];
    float mu = tot1 * (1.0f / CF);
    float var = tot2 * (1.0f / CF) - mu * mu;
    float rs = rsqrtf(var + 1e-5f);
    float xh = (v - mu) * rs * lnw[i] + lnb[i];
    float si = silu_f(xh);
    float bs[8]; bspline8(xh, bs);
    float p0 = si * cbw[i], p1 = si * cbw[CF + i];
    float sp0 = 0.f, sp1 = 0.f;
#pragma unroll
    for (int c = 0; c < 8; ++c) {
        sp0 += bs[c] * csw[(size_t)i * 8 + c];
        sp1 += bs[c] * csw[(size_t)(CF + i) * 8 + c];
    }
    p0 += sp0 * csc[i];
    p1 += sp1 * csc[CF + i];
#pragma unroll
    for (int off = 32; off > 0; off >>= 1) {
        p0 += __shfl_xor(p0, off);
        p1 += __shfl_xor(p1, off);
    }
    if (lane == 0) { rP0[wid] = p0; rP1[wid] = p1; }
    __syncthreads();
    if (i == 0) {
        lblk[n * 2 + 0] = rP0[0] + rP0[1] + rP0[2] + rP0[3];
        lblk[n * 2 + 1] = rP1[0] + rP1[1] + rP1[2] + rP1[3];
    }
}

// ---- 7. per-batch confidence softmax + weighted sum ------------------------
__global__ __launch_bounds__(64) void final_kernel(const float* __restrict__ conf,
                                                   const float* __restrict__ lblk,
                                                   float* __restrict__ out) {
    int b = blockIdx.x, p = threadIdx.x;
    float cf = conf[b * 64 + p];
    float mx = cf;
#pragma unroll
    for (int off = 32; off > 0; off >>= 1) mx = fmaxf(mx, __shfl_xor(mx, off));
    float ev = expf(cf - mx);
    float s = ev;
#pragma unroll
    for (int off = 32; off > 0; off >>= 1) s += __shfl_xor(s, off);
    float w = ev / s;
    float l0 = w * lblk[(b * 64 + p) * 2 + 0];
    float l1 = w * lblk[(b * 64 + p) * 2 + 1];
#pragma unroll
    for (int off = 32; off > 0; off >>= 1) {
        l0 += __shfl_xor(l0, off);
        l1 += __shfl_xor(l1, off);
    }
    if (p == 0) { out[b * 2 + 0] = l0; out[b * 2 + 1] = l1; }
}

extern "C" void kernel_launch(void* const* d_in, const int* in_sizes, int n_in,
                              void* d_out, int out_size, void* d_ws, size_t ws_size,
                              hipStream_t stream) {
    const float* fpn      = (const float*)d_in[0];
    const float* seg      = (const float*)d_in[1];
    const float* ln_r_w   = (const float*)d_in[2];
    const float* ln_r_b   = (const float*)d_in[3];
    const float* ln_h_w   = (const float*)d_in[4];
    const float* ln_h_b   = (const float*)d_in[5];
    const float* router_w = (const float*)d_in[6];
    const float* router_b = (const float*)d_in[7];
    const float* bw1      = (const float*)d_in[8];
    const float* sw1      = (const float*)d_in[9];
    const float* sc1      = (const float*)d_in[10];
    const float* bw2      = (const float*)d_in[11];
    const float* sw2      = (const float*)d_in[12];
    const float* sc2      = (const float*)d_in[13];
    const float* cls_bw   = (const float*)d_in[14];
    const float* cls_sw   = (const float*)d_in[15];
    const float* cls_sc   = (const float*)d_in[16];

    float* ws = (float*)d_ws;
    // common small buffers
    float* vec   = ws;                  // 131072
    float* xnorm = vec + 131072;        // 131072
    float* cw    = xnorm + 131072;      // 4096
    float* conf  = cw + 4096;           // 512
    float* lblk  = conf + 512;          // 1024
    float* outc  = lblk + 1024;         // 131072
    // W2 persists through gemm2
    float* W2    = outc + 131072;                   // 8*256*1536 = 3145728
    // region X: A1+W1 (gemm1 phase) overlapped with A2 (gemm2 phase)
    float* X     = W2 + (size_t)NE * CF * K2P;
    float* A1    = X;                               // 512*2304  = 1179648
    float* W1    = X + (size_t)NTOK * K1;           // 8*170*2304 = 3133440
    float* A2    = X;                               // 8*512*1536 = 6291456 (reuses A1+W1 after gemm1)
    float* Hbuf  = X + (size_t)NE * NTOK * K2P;     // 8*512*170 = 696320
    float* yall  = Hbuf + (size_t)NE * NTOK * HID;  // 8*512*256 = 1048576

    pool_kernel<<<dim3(CF, 8), dim3(256), 0, stream>>>(fpn, seg, vec);
    buildW1_kernel<<<dim3(HID, NE), dim3(256), 0, stream>>>(bw1, sw1, sc1, W1);
    buildW2_kernel<<<dim3(CF, NE), dim3(192), 0, stream>>>(bw2, sw2, sc2, W2);
    router_kernel<<<dim3(1), dim3(512), 0, stream>>>(vec, ln_r_w, ln_r_b, router_w, router_b,
                                                     xnorm, cw, conf);
    buildA1_kernel<<<dim3(NTOK), dim3(256), 0, stream>>>(xnorm, A1);
    gemm_nt_kernel<<<dim3(3, 8, NE), dim3(256), 0, stream>>>(
        A1, W1, Hbuf, HID, K1, K1, K1, HID, 0L, (long)HID * K1, (long)NTOK * HID, 1);
    buildA2_kernel<<<dim3(NTOK, NE), dim3(192), 0, stream>>>(Hbuf, A2);
    gemm_nt_kernel<<<dim3(4, 8, NE), dim3(256), 0, stream>>>(
        A2, W2, yall, CF, K2P, K2P, K2P, CF, (long)NTOK * K2P, (long)CF * K2P, (long)NTOK * CF, 0);
    combine_kernel<<<dim3(NTOK), dim3(256), 0, stream>>>(yall, cw, outc);
    cls_kernel<<<dim3(NTOK), dim3(256), 0, stream>>>(outc, ln_h_w, ln_h_b, cls_bw, cls_sw, cls_sc,
                                                     lblk);
    final_kernel<<<dim3(8), dim3(64), 0, stream>>>(conf, lblk, (float*)d_out);
}

// Round 2
// 132.310 us; speedup vs baseline: 3.4322x; 3.4322x over previous
//
#include <hip/hip_runtime.h>
#include <math.h>

#define CF 256
#define HID 170
#define NE 8
#define NTOK 512
#define K1 2304      // 256*9
#define K2P 1536     // 170*9 = 1530 padded to 1536
#define CAPACITY 161

typedef __bf16 bf16x8 __attribute__((ext_vector_type(8)));
typedef unsigned short u16x8 __attribute__((ext_vector_type(8)));
typedef float f32x4 __attribute__((ext_vector_type(4)));

__device__ __forceinline__ float silu_f(float x) { return x / (1.0f + expf(-x)); }

__device__ __forceinline__ unsigned short f2bf(float f) {
    unsigned int u = __float_as_uint(f);
    u = u + 0x7fffu + ((u >> 16) & 1u);
    return (unsigned short)(u >> 16);
}

// Cubic B-spline bases on uniform grid g(j) = (j-3)*0.4 - 1; denominators are k*h
__device__ __forceinline__ void bspline8(float x, float bs[8]) {
    float b[11];
#pragma unroll
    for (int j = 0; j < 11; ++j) {
        float g0 = (float)(j - 3) * 0.4f - 1.0f;
        float g1 = (float)(j - 2) * 0.4f - 1.0f;
        b[j] = (x >= g0 && x < g1) ? 1.0f : 0.0f;
    }
#pragma unroll
    for (int k = 1; k <= 3; ++k) {
        float inv = 2.5f / (float)k;  // 1/(k*0.4)
#pragma unroll
        for (int j = 0; j < 10 - (k - 1); ++j) {
            float gj   = (float)(j - 3) * 0.4f - 1.0f;
            float gjk1 = (float)(j - 2 + k) * 0.4f - 1.0f;
            b[j] = (x - gj) * inv * b[j] + (gjk1 - x) * inv * b[j + 1];
        }
    }
#pragma unroll
    for (int c = 0; c < 8; ++c) bs[c] = b[c];
}

// ---- 1. pooling ------------------------------------------------------------
__global__ __launch_bounds__(256) void pool_kernel(const float* __restrict__ fpn,
                                                   const float* __restrict__ seg,
                                                   float* __restrict__ vec) {
    int c = blockIdx.x, b = blockIdx.y, tid = threadIdx.x;
    const float* src = (c < 254) ? fpn + (size_t)(b * 254 + c) * 32768
                                 : seg + (size_t)(b * 2 + (c - 254)) * 32768;
    const float4* s4 = (const float4*)src;
    float s[4] = {0.f, 0.f, 0.f, 0.f};
#pragma unroll
    for (int it = 0; it < 32; ++it) {
        float4 v = s4[it * 256 + tid];
        s[it >> 3] += v.x + v.y + v.z + v.w;
    }
    __shared__ float acc[64];
    if (tid < 64) acc[tid] = 0.0f;
    __syncthreads();
    int bh = tid >> 6, bw = (tid & 7) >> 1;
#pragma unroll
    for (int bd = 0; bd < 4; ++bd) atomicAdd(&acc[bd * 16 + bh * 4 + bw], s[bd]);
    __syncthreads();
    if (tid < 64) vec[(size_t)(b * 64 + tid) * CF + c] = acc[tid] * (1.0f / 512.0f);
}

// ---- 2a. per-token layernorm + router scores -------------------------------
__global__ __launch_bounds__(256) void ln_score_kernel(const float* __restrict__ vec,
                                                       const float* __restrict__ lnw,
                                                       const float* __restrict__ lnb,
                                                       const float* __restrict__ rw,
                                                       const float* __restrict__ rb,
                                                       float* __restrict__ xnorm,
                                                       float* __restrict__ scores) {
    int n = blockIdx.x, i = threadIdx.x;
    float v = vec[(size_t)n * CF + i];
    float s1 = v, s2 = v * v;
#pragma unroll
    for (int off = 32; off > 0; off >>= 1) {
        s1 += __shfl_xor(s1, off);
        s2 += __shfl_xor(s2, off);
    }
    __shared__ float rs1[4], rs2[4];
    int lane = i & 63, wid = i >> 6;
    if (lane == 0) { rs1[wid] = s1; rs2[wid] = s2; }
    __syncthreads();
    float tot1 = rs1[0] + rs1[1] + rs1[2] + rs1[3];
    float tot2 = rs2[0] + rs2[1] + rs2[2] + rs2[3];
    float mu = tot1 * (1.0f / CF);
    float var = tot2 * (1.0f / CF) - mu * mu;
    float rsd = rsqrtf(var + 1e-5f);
    float xv = (v - mu) * rsd * lnw[i] + lnb[i];
    xnorm[(size_t)n * CF + i] = xv;
    float p[NE];
#pragma unroll
    for (int e = 0; e < NE; ++e) p[e] = xv * rw[e * CF + i];
#pragma unroll
    for (int off = 32; off > 0; off >>= 1)
#pragma unroll
        for (int e = 0; e < NE; ++e) p[e] += __shfl_xor(p[e], off);
    __shared__ float pacc[4][NE];
    if (lane == 0)
#pragma unroll
        for (int e = 0; e < NE; ++e) pacc[wid][e] = p[e];
    __syncthreads();
    if (i < NE)
        scores[n * NE + i] = pacc[0][i] + pacc[1][i] + pacc[2][i] + pacc[3][i] + rb[i];
}

// ---- 2b. top-2 + softmax weights + capacity (ballot prefix) ----------------
__global__ __launch_bounds__(512) void topk_kernel(const float* __restrict__ scores,
                                                   float* __restrict__ cw,
                                                   float* __restrict__ conf) {
    int n = threadIdx.x;
    __shared__ int   ti0[NTOK], ti1[NTOK];
    __shared__ float tw0[NTOK], tw1[NTOK];
    float m1 = -1e30f, m2 = -1e30f; int i1 = 0, i2 = 0;
#pragma unroll
    for (int e = 0; e < NE; ++e) {
        float sc = scores[n * NE + e];
        if (sc > m1) { m2 = m1; i2 = i1; m1 = sc; i1 = e; }
        else if (sc > m2) { m2 = sc; i2 = e; }
    }
    conf[n] = m1;
    float ew = expf(m2 - m1);
    ti0[n] = i1; ti1[n] = i2;
    tw0[n] = 1.0f / (1.0f + ew); tw1[n] = ew / (1.0f + ew);
    __syncthreads();
    int e = n >> 6, lane = n & 63;  // one wave per expert
    int cnt = 0;
    for (int c = 0; c < NTOK / 64; ++c) {
        int t = c * 64 + lane;
        int h0 = (ti0[t] == e), h1 = (ti1[t] == e);
        int sel = h0 | h1;
        unsigned long long mask = __ballot(sel);
        int pos = cnt + (int)__popcll(mask & ((1ull << lane) - 1ull));
        float wv = 0.f;
        if (sel && pos < CAPACITY) wv = h0 ? tw0[t] : tw1[t];
        cw[e * NTOK + t] = wv;
        cnt += (int)__popcll(mask);
    }
}

// ---- 3. build augmented bf16 activations / weights -------------------------
__global__ __launch_bounds__(256) void buildA1_kernel(const float* __restrict__ xnorm,
                                                      unsigned short* __restrict__ A1) {
    int n = blockIdx.x, i = threadIdx.x;
    float x = xnorm[(size_t)n * CF + i];
    unsigned short* r = A1 + (size_t)n * K1;
    r[i] = f2bf(silu_f(x));
    float bs[8]; bspline8(x, bs);
    unsigned short* sp = r + CF + i * 8;
#pragma unroll
    for (int c = 0; c < 8; ++c) sp[c] = f2bf(bs[c]);
}

__global__ __launch_bounds__(256) void buildW1_kernel(const float* __restrict__ bw1,
                                                      const float* __restrict__ sw1,
                                                      const float* __restrict__ sc1,
                                                      unsigned short* __restrict__ W1) {
    int o = blockIdx.x, e = blockIdx.y, i = threadIdx.x;
    size_t oi = (size_t)(e * HID + o) * CF + i;
    unsigned short* r = W1 + (size_t)(e * HID + o) * K1;
    r[i] = f2bf(bw1[oi]);
    float sc = sc1[oi];
    const float* sw = sw1 + oi * 8;
    unsigned short* sp = r + CF + i * 8;
#pragma unroll
    for (int c = 0; c < 8; ++c) sp[c] = f2bf(sw[c] * sc);
}

__global__ __launch_bounds__(192) void buildW2_kernel(const float* __restrict__ bw2,
                                                      const float* __restrict__ sw2,
                                                      const float* __restrict__ sc2,
                                                      unsigned short* __restrict__ W2) {
    int o = blockIdx.x, e = blockIdx.y, t = threadIdx.x;
    unsigned short* r = W2 + (size_t)(e * CF + o) * K2P;
    if (t < HID) {
        size_t oi = (size_t)(e * CF + o) * HID + t;
        r[t] = f2bf(bw2[oi]);
        float sc = sc2[oi];
        const float* sw = sw2 + oi * 8;
        unsigned short* sp = r + HID + t * 8;
#pragma unroll
        for (int c = 0; c < 8; ++c) sp[c] = f2bf(sw[c] * sc);
    } else if (t < HID + 6) {
        r[HID * 9 + (t - HID)] = 0;
    }
}

__global__ __launch_bounds__(192) void buildA2_kernel(const float* __restrict__ H,
                                                      unsigned short* __restrict__ A2) {
    int n = blockIdx.x, e = blockIdx.y, t = threadIdx.x;
    unsigned short* r = A2 + (size_t)(e * NTOK + n) * K2P;
    if (t < HID) {
        float h = H[(size_t)(e * NTOK + n) * HID + t];
        r[t] = f2bf(silu_f(h));
        float bs[8]; bspline8(h, bs);
        unsigned short* sp = r + HID + t * 8;
#pragma unroll
        for (int c = 0; c < 8; ++c) sp[c] = f2bf(bs[c]);
    } else if (t < HID + 6) {
        r[HID * 9 + (t - HID)] = 0;
    }
}

// ---- 4. batched bf16 MFMA GEMM: C[e] = A[e] (M,K) * B[e] (N,K)^T -----------
// 64x64 tile, BK=64, 4 waves (2x2), each wave 32x32 via 2x2 16x16x32 frags.
__global__ __launch_bounds__(256) void gemm_mfma_kernel(const unsigned short* __restrict__ Ag,
                                                        const unsigned short* __restrict__ Bg,
                                                        float* __restrict__ C,
                                                        int N, int K, long sA, long sB, long sC,
                                                        int ldc, int act) {
    int e = blockIdx.z;
    const unsigned short* A = Ag + (size_t)e * sA;
    const unsigned short* B = Bg + (size_t)e * sB;
    C += (size_t)e * sC;
    int m0 = blockIdx.y * 64, n0 = blockIdx.x * 64;

    __shared__ alignas(16) unsigned char AsB[8192];
    __shared__ alignas(16) unsigned char BsB[8192];

    int tid = threadIdx.x;
    int lane = tid & 63, w = tid >> 6;
    int wr = w >> 1, wc = w & 1;
    int fr = lane & 15, fg = lane >> 4;
    int srow = tid >> 3;        // 0..31
    int schunk = tid & 7;       // 0..7 (16B chunks within 128B row)

    // precomputed swizzled staging byte offsets
    int r0 = srow, r1 = srow + 32;
    int wb0 = r0 * 128 + ((schunk * 16) ^ ((r0 & 7) << 4));
    int wb1 = r1 * 128 + ((schunk * 16) ^ ((r1 & 7) << 4));

    f32x4 acc[2][2];
#pragma unroll
    for (int i = 0; i < 2; ++i)
#pragma unroll
        for (int j = 0; j < 2; ++j)
#pragma unroll
            for (int r = 0; r < 4; ++r) acc[i][j][r] = 0.f;

    for (int k0 = 0; k0 < K; k0 += 64) {
        u16x8 a0 = *(const u16x8*)(A + (size_t)(m0 + r0) * K + k0 + schunk * 8);
        u16x8 a1 = *(const u16x8*)(A + (size_t)(m0 + r1) * K + k0 + schunk * 8);
        u16x8 b0 = {0, 0, 0, 0, 0, 0, 0, 0};
        u16x8 b1 = {0, 0, 0, 0, 0, 0, 0, 0};
        int bn0 = n0 + r0, bn1 = n0 + r1;
        if (bn0 < N) b0 = *(const u16x8*)(B + (size_t)bn0 * K + k0 + schunk * 8);
        if (bn1 < N) b1 = *(const u16x8*)(B + (size_t)bn1 * K + k0 + schunk * 8);
        __syncthreads();
        *(u16x8*)(AsB + wb0) = a0;
        *(u16x8*)(AsB + wb1) = a1;
        *(u16x8*)(BsB + wb0) = b0;
        *(u16x8*)(BsB + wb1) = b1;
        __syncthreads();
#pragma unroll
        for (int ks = 0; ks < 2; ++ks) {
            int kb = ks * 64 + fg * 16;
            u16x8 af[2], bf[2];
#pragma unroll
            for (int mf = 0; mf < 2; ++mf) {
                int row = wr * 32 + mf * 16 + fr;
                af[mf] = *(const u16x8*)(AsB + row * 128 + (kb ^ ((row & 7) << 4)));
            }
#pragma unroll
            for (int nf = 0; nf < 2; ++nf) {
                int row = wc * 32 + nf * 16 + fr;
                bf[nf] = *(const u16x8*)(BsB + row * 128 + (kb ^ ((row & 7) << 4)));
            }
#pragma unroll
            for (int mf = 0; mf < 2; ++mf)
#pragma unroll
                for (int nf = 0; nf < 2; ++nf)
                    acc[mf][nf] = __builtin_amdgcn_mfma_f32_16x16x32_bf16(
                        __builtin_bit_cast(bf16x8, af[mf]),
                        __builtin_bit_cast(bf16x8, bf[nf]), acc[mf][nf], 0, 0, 0);
        }
    }
#pragma unroll
    for (int mf = 0; mf < 2; ++mf)
#pragma unroll
        for (int nf = 0; nf < 2; ++nf)
#pragma unroll
            for (int r = 0; r < 4; ++r) {
                int row = m0 + wr * 32 + mf * 16 + fg * 4 + r;
                int col = n0 + wc * 32 + nf * 16 + fr;
                if (col < N) {
                    float v = acc[mf][nf][r];
                    if (act) v = 0.5f * v * (1.0f + erff(v * 0.70710678118654752f));
                    C[(size_t)row * ldc + col] = v;
                }
            }
}

// ---- 5. combine experts ----------------------------------------------------
__global__ __launch_bounds__(256) void combine_kernel(const float* __restrict__ y,
                                                      const float* __restrict__ cw,
                                                      float* __restrict__ outc) {
    int n = blockIdx.x, c = threadIdx.x;
    float a = 0.f;
#pragma unroll
    for (int e = 0; e < NE; ++e)
        a += cw[e * NTOK + n] * y[((size_t)(e * NTOK + n)) * CF + c];
    outc[(size_t)n * CF + c] = a;
}

// ---- 6. classifier KAN -----------------------------------------------------
__global__ __launch_bounds__(256) void cls_kernel(const float* __restrict__ outc,
                                                  const float* __restrict__ lnw,
                                                  const float* __restrict__ lnb,
                                                  const float* __restrict__ cbw,
                                                  const float* __restrict__ csw,
                                                  const float* __restrict__ csc,
                                                  float* __restrict__ lblk) {
    int n = blockIdx.x, i = threadIdx.x;
    float v = outc[(size_t)n * CF + i];
    float s1 = v, s2 = v * v;
#pragma unroll
    for (int off = 32; off > 0; off >>= 1) {
        s1 += __shfl_xor(s1, off);
        s2 += __shfl_xor(s2, off);
    }
    __shared__ float rA[4], rB[4], rP0[4], rP1[4];
    int lane = i & 63, wid = i >> 6;
    if (lane == 0) { rA[wid] = s1; rB[wid] = s2; }
    __syncthreads();
    float tot1 = rA[0] + rA[1] + rA[2] + rA[3];
    float tot2 = rB[0] + rB[1] + rB[2] + rB[3];
    float mu = tot1 * (1.0f / CF);
    float var = tot2 * (1.0f / CF) - mu * mu;
    float rs = rsqrtf(var + 1e-5f);
    float xh = (v - mu) * rs * lnw[i] + lnb[i];
    float si = silu_f(xh);
    float bs[8]; bspline8(xh, bs);
    float p0 = si * cbw[i], p1 = si * cbw[CF + i];
    float sp0 = 0.f, sp1 = 0.f;
#pragma unroll
    for (int c = 0; c < 8; ++c) {
        sp0 += bs[c] * csw[(size_t)i * 8 + c];
        sp1 += bs[c] * csw[(size_t)(CF + i) * 8 + c];
    }
    p0 += sp0 * csc[i];
    p1 += sp1 * csc[CF + i];
#pragma unroll
    for (int off = 32; off > 0; off >>= 1) {
        p0 += __shfl_xor(p0, off);
        p1 += __shfl_xor(p1, off);
    }
    if (lane == 0) { rP0[wid] = p0; rP1[wid] = p1; }
    __syncthreads();
    if (i == 0) {
        lblk[n * 2 + 0] = rP0[0] + rP0[1] + rP0[2] + rP0[3];
        lblk[n * 2 + 1] = rP1[0] + rP1[1] + rP1[2] + rP1[3];
    }
}

// ---- 7. per-batch confidence softmax + weighted sum ------------------------
__global__ __launch_bounds__(64) void final_kernel(const float* __restrict__ conf,
                                                   const float* __restrict__ lblk,
                                                   float* __restrict__ out) {
    int b = blockIdx.x, p = threadIdx.x;
    float cf = conf[b * 64 + p];
    float mx = cf;
#pragma unroll
    for (int off = 32; off > 0; off >>= 1) mx = fmaxf(mx, __shfl_xor(mx, off));
    float ev = expf(cf - mx);
    float s = ev;
#pragma unroll
    for (int off = 32; off > 0; off >>= 1) s += __shfl_xor(s, off);
    float w = ev / s;
    float l0 = w * lblk[(b * 64 + p) * 2 + 0];
    float l1 = w * lblk[(b * 64 + p) * 2 + 1];
#pragma unroll
    for (int off = 32; off > 0; off >>= 1) {
        l0 += __shfl_xor(l0, off);
        l1 += __shfl_xor(l1, off);
    }
    if (p == 0) { out[b * 2 + 0] = l0; out[b * 2 + 1] = l1; }
}

extern "C" void kernel_launch(void* const* d_in, const int* in_sizes, int n_in,
                              void* d_out, int out_size, void* d_ws, size_t ws_size,
                              hipStream_t stream) {
    const float* fpn      = (const float*)d_in[0];
    const float* seg      = (const float*)d_in[1];
    const float* ln_r_w   = (const float*)d_in[2];
    const float* ln_r_b   = (const float*)d_in[3];
    const float* ln_h_w   = (const float*)d_in[4];
    const float* ln_h_b   = (const float*)d_in[5];
    const float* router_w = (const float*)d_in[6];
    const float* router_b = (const float*)d_in[7];
    const float* bw1      = (const float*)d_in[8];
    const float* sw1      = (const float*)d_in[9];
    const float* sc1      = (const float*)d_in[10];
    const float* bw2      = (const float*)d_in[11];
    const float* sw2      = (const float*)d_in[12];
    const float* sc2      = (const float*)d_in[13];
    const float* cls_bw   = (const float*)d_in[14];
    const float* cls_sw   = (const float*)d_in[15];
    const float* cls_sc   = (const float*)d_in[16];

    float* ws = (float*)d_ws;
    float* vec    = ws;                    // 131072
    float* xnorm  = vec + 131072;          // 131072
    float* scores = xnorm + 131072;        // 4096
    float* cw     = scores + 4096;         // 4096
    float* conf   = cw + 4096;             // 512
    float* lblk   = conf + 512;            // 1024
    float* outc   = lblk + 1024;           // 131072
    float* Hbuf   = outc + 131072;         // 8*512*170 = 696320
    float* yall   = Hbuf + 696320;         // 8*512*256 = 1048576
    unsigned short* A1b = (unsigned short*)(yall + 1048576);   // 512*2304
    unsigned short* W1b = A1b + (size_t)NTOK * K1;             // 8*170*2304
    unsigned short* A2b = W1b + (size_t)NE * HID * K1;         // 8*512*1536
    unsigned short* W2b = A2b + (size_t)NE * NTOK * K2P;       // 8*256*1536

    pool_kernel<<<dim3(CF, 8), dim3(256), 0, stream>>>(fpn, seg, vec);
    buildW1_kernel<<<dim3(HID, NE), dim3(256), 0, stream>>>(bw1, sw1, sc1, W1b);
    buildW2_kernel<<<dim3(CF, NE), dim3(192), 0, stream>>>(bw2, sw2, sc2, W2b);
    ln_score_kernel<<<dim3(NTOK), dim3(256), 0, stream>>>(vec, ln_r_w, ln_r_b, router_w,
                                                          router_b, xnorm, scores);
    topk_kernel<<<dim3(1), dim3(512), 0, stream>>>(scores, cw, conf);
    buildA1_kernel<<<dim3(NTOK), dim3(256), 0, stream>>>(xnorm, A1b);
    gemm_mfma_kernel<<<dim3(3, 8, NE), dim3(256), 0, stream>>>(
        A1b, W1b, Hbuf, HID, K1, 0L, (long)HID * K1, (long)NTOK * HID, HID, 1);
    buildA2_kernel<<<dim3(NTOK, NE), dim3(192), 0, stream>>>(Hbuf, A2b);
    gemm_mfma_kernel<<<dim3(4, 8, NE), dim3(256), 0, stream>>>(
        A2b, W2b, yall, CF, K2P, (long)NTOK * K2P, (long)CF * K2P, (long)NTOK * CF, CF, 0);
    combine_kernel<<<dim3(NTOK), dim3(256), 0, stream>>>(yall, cw, outc);
    cls_kernel<<<dim3(NTOK), dim3(256), 0, stream>>>(outc, ln_h_w, ln_h_b, cls_bw, cls_sw,
                                                     cls_sc, lblk);
    final_kernel<<<dim3(8), dim3(64), 0, stream>>>(conf, lblk, (float*)d_out);
}

// Round 3
// 117.145 us; speedup vs baseline: 3.8765x; 1.1295x over previous
//
#include <hip/hip_runtime.h>
#include <math.h>

#define CF 256
#define HID 170
#define NE 8
#define NTOK 512
#define K1 2304      // 256*9
#define K2P 1536     // 170*9 = 1530 padded to 1536
#define CAPACITY 161

typedef __bf16 bf16x8 __attribute__((ext_vector_type(8)));
typedef unsigned short u16x8 __attribute__((ext_vector_type(8)));
typedef float f32x4 __attribute__((ext_vector_type(4)));

__device__ __forceinline__ float silu_f(float x) { return x / (1.0f + expf(-x)); }
__device__ __forceinline__ float gelu_f(float x) {
    return 0.5f * x * (1.0f + erff(x * 0.70710678118654752f));
}

__device__ __forceinline__ unsigned short f2bf(float f) {
    unsigned int u = __float_as_uint(f);
    u = u + 0x7fffu + ((u >> 16) & 1u);
    return (unsigned short)(u >> 16);
}

// Cubic B-spline bases on uniform grid g(j) = (j-3)*0.4 - 1; denominators are k*h
__device__ __forceinline__ void bspline8(float x, float bs[8]) {
    float b[11];
#pragma unroll
    for (int j = 0; j < 11; ++j) {
        float g0 = (float)(j - 3) * 0.4f - 1.0f;
        float g1 = (float)(j - 2) * 0.4f - 1.0f;
        b[j] = (x >= g0 && x < g1) ? 1.0f : 0.0f;
    }
#pragma unroll
    for (int k = 1; k <= 3; ++k) {
        float inv = 2.5f / (float)k;  // 1/(k*0.4)
#pragma unroll
        for (int j = 0; j < 10 - (k - 1); ++j) {
            float gj   = (float)(j - 3) * 0.4f - 1.0f;
            float gjk1 = (float)(j - 2 + k) * 0.4f - 1.0f;
            b[j] = (x - gj) * inv * b[j] + (gjk1 - x) * inv * b[j + 1];
        }
    }
#pragma unroll
    for (int c = 0; c < 8; ++c) bs[c] = b[c];
}

// ---- 1. mega: pool (blocks 0..2047) + buildW1 (..3407) + buildW2 (..5455) --
__global__ __launch_bounds__(256) void mega_front_kernel(const float* __restrict__ fpn,
                                                         const float* __restrict__ seg,
                                                         const float* __restrict__ bw1,
                                                         const float* __restrict__ sw1,
                                                         const float* __restrict__ sc1,
                                                         const float* __restrict__ bw2,
                                                         const float* __restrict__ sw2,
                                                         const float* __restrict__ sc2,
                                                         float* __restrict__ vec,
                                                         unsigned short* __restrict__ W1,
                                                         unsigned short* __restrict__ W2) {
    int id = blockIdx.x, tid = threadIdx.x;
    if (id < 2048) {
        // ---- pool ----
        int c = id & 255, b = id >> 8;
        const float* src = (c < 254) ? fpn + (size_t)(b * 254 + c) * 32768
                                     : seg + (size_t)(b * 2 + (c - 254)) * 32768;
        const float4* s4 = (const float4*)src;
        float s[4] = {0.f, 0.f, 0.f, 0.f};
#pragma unroll
        for (int it = 0; it < 32; ++it) {
            float4 v = s4[it * 256 + tid];
            s[it >> 3] += v.x + v.y + v.z + v.w;
        }
        __shared__ float acc[64];
        if (tid < 64) acc[tid] = 0.0f;
        __syncthreads();
        int bh = tid >> 6, bw = (tid & 7) >> 1;
#pragma unroll
        for (int bd = 0; bd < 4; ++bd) atomicAdd(&acc[bd * 16 + bh * 4 + bw], s[bd]);
        __syncthreads();
        if (tid < 64) vec[(size_t)(b * 64 + tid) * CF + c] = acc[tid] * (1.0f / 512.0f);
    } else if (id < 2048 + NE * HID) {
        // ---- build W1 (augmented bf16) ----
        int r = id - 2048;
        int o = r % HID, e = r / HID, i = tid;
        size_t oi = (size_t)(e * HID + o) * CF + i;
        unsigned short* row = W1 + (size_t)(e * HID + o) * K1;
        row[i] = f2bf(bw1[oi]);
        float sc = sc1[oi];
        const float* sw = sw1 + oi * 8;
        u16x8 pk;
#pragma unroll
        for (int c = 0; c < 8; ++c) pk[c] = f2bf(sw[c] * sc);
        *(u16x8*)(row + CF + i * 8) = pk;
    } else {
        // ---- build W2 (augmented bf16, K padded to 1536) ----
        int r = id - (2048 + NE * HID);
        int o = r & 255, e = r >> 8, t = tid;
        unsigned short* row = W2 + (size_t)(e * CF + o) * K2P;
        if (t < HID) {
            size_t oi = (size_t)(e * CF + o) * HID + t;
            row[t] = f2bf(bw2[oi]);
            float sc = sc2[oi];
            const float* sw = sw2 + oi * 8;
            u16x8 pk;
#pragma unroll
            for (int c = 0; c < 8; ++c) pk[c] = f2bf(sw[c] * sc);
            *(u16x8*)(row + HID + t * 8) = pk;
        } else if (t < HID + 6) {
            row[HID * 9 + (t - HID)] = 0;
        }
    }
}

// ---- 2a. per-token layernorm + router scores + A1 build --------------------
__global__ __launch_bounds__(256) void ln_score_a1_kernel(const float* __restrict__ vec,
                                                          const float* __restrict__ lnw,
                                                          const float* __restrict__ lnb,
                                                          const float* __restrict__ rw,
                                                          const float* __restrict__ rb,
                                                          float* __restrict__ scores,
                                                          unsigned short* __restrict__ A1) {
    int n = blockIdx.x, i = threadIdx.x;
    float v = vec[(size_t)n * CF + i];
    float s1 = v, s2 = v * v;
#pragma unroll
    for (int off = 32; off > 0; off >>= 1) {
        s1 += __shfl_xor(s1, off);
        s2 += __shfl_xor(s2, off);
    }
    __shared__ float rs1[4], rs2[4];
    int lane = i & 63, wid = i >> 6;
    if (lane == 0) { rs1[wid] = s1; rs2[wid] = s2; }
    __syncthreads();
    float tot1 = rs1[0] + rs1[1] + rs1[2] + rs1[3];
    float tot2 = rs2[0] + rs2[1] + rs2[2] + rs2[3];
    float mu = tot1 * (1.0f / CF);
    float var = tot2 * (1.0f / CF) - mu * mu;
    float rsd = rsqrtf(var + 1e-5f);
    float xv = (v - mu) * rsd * lnw[i] + lnb[i];
    // A1 row (silu + 8 spline bases, bf16)
    unsigned short* r = A1 + (size_t)n * K1;
    r[i] = f2bf(silu_f(xv));
    float bs[8]; bspline8(xv, bs);
    u16x8 pk;
#pragma unroll
    for (int c = 0; c < 8; ++c) pk[c] = f2bf(bs[c]);
    *(u16x8*)(r + CF + i * 8) = pk;
    // router scores
    float p[NE];
#pragma unroll
    for (int e = 0; e < NE; ++e) p[e] = xv * rw[e * CF + i];
#pragma unroll
    for (int off = 32; off > 0; off >>= 1)
#pragma unroll
        for (int e = 0; e < NE; ++e) p[e] += __shfl_xor(p[e], off);
    __shared__ float pacc[4][NE];
    if (lane == 0)
#pragma unroll
        for (int e = 0; e < NE; ++e) pacc[wid][e] = p[e];
    __syncthreads();
    if (i < NE)
        scores[n * NE + i] = pacc[0][i] + pacc[1][i] + pacc[2][i] + pacc[3][i] + rb[i];
}

// ---- 2b. top-2 + softmax weights + capacity (ballot prefix) ----------------
__global__ __launch_bounds__(512) void topk_kernel(const float* __restrict__ scores,
                                                   float* __restrict__ cw,
                                                   float* __restrict__ conf) {
    int n = threadIdx.x;
    __shared__ int   ti0[NTOK], ti1[NTOK];
    __shared__ float tw0[NTOK], tw1[NTOK];
    float m1 = -1e30f, m2 = -1e30f; int i1 = 0, i2 = 0;
#pragma unroll
    for (int e = 0; e < NE; ++e) {
        float sc = scores[n * NE + e];
        if (sc > m1) { m2 = m1; i2 = i1; m1 = sc; i1 = e; }
        else if (sc > m2) { m2 = sc; i2 = e; }
    }
    conf[n] = m1;
    float ew = expf(m2 - m1);
    ti0[n] = i1; ti1[n] = i2;
    tw0[n] = 1.0f / (1.0f + ew); tw1[n] = ew / (1.0f + ew);
    __syncthreads();
    int e = n >> 6, lane = n & 63;  // one wave per expert
    int cnt = 0;
    for (int c = 0; c < NTOK / 64; ++c) {
        int t = c * 64 + lane;
        int h0 = (ti0[t] == e), h1 = (ti1[t] == e);
        int sel = h0 | h1;
        unsigned long long mask = __ballot(sel);
        int pos = cnt + (int)__popcll(mask & ((1ull << lane) - 1ull));
        float wv = 0.f;
        if (sel && pos < CAPACITY) wv = h0 ? tw0[t] : tw1[t];
        cw[e * NTOK + t] = wv;
        cnt += (int)__popcll(mask);
    }
}

// ---- 4. batched bf16 MFMA GEMM, reg-prefetch double buffer -----------------
// C[e] = A[e](M,K) * B[e](N,K)^T. 64x64 tile, BK=64, 4 waves (2x2).
// mode 1: epilogue = gelu -> emit augmented bf16 A2 row (silu + 8 bases)
// mode 0: epilogue = plain f32 store to C
__global__ __launch_bounds__(256) void gemm_mfma_kernel(const unsigned short* __restrict__ Ag,
                                                        const unsigned short* __restrict__ Bg,
                                                        float* __restrict__ C,
                                                        unsigned short* __restrict__ A2,
                                                        int N, int K, long sA, long sB, long sC,
                                                        int ldc, int mode) {
    int e = blockIdx.z;
    const unsigned short* A = Ag + (size_t)e * sA;
    const unsigned short* B = Bg + (size_t)e * sB;
    int m0 = blockIdx.y * 64, n0 = blockIdx.x * 64;

    __shared__ alignas(16) unsigned char AsB[8192];
    __shared__ alignas(16) unsigned char BsB[8192];

    int tid = threadIdx.x;
    int lane = tid & 63, w = tid >> 6;
    int wr = w >> 1, wc = w & 1;
    int fr = lane & 15, fg = lane >> 4;
    int srow = tid >> 3;        // 0..31
    int schunk = tid & 7;       // 0..7 (16B chunks within 128B row)

    int r0 = srow, r1 = srow + 32;
    int wb0 = r0 * 128 + ((schunk * 16) ^ ((r0 & 7) << 4));
    int wb1 = r1 * 128 + ((schunk * 16) ^ ((r1 & 7) << 4));

    f32x4 acc[2][2];
#pragma unroll
    for (int i = 0; i < 2; ++i)
#pragma unroll
        for (int j = 0; j < 2; ++j)
#pragma unroll
            for (int r = 0; r < 4; ++r) acc[i][j][r] = 0.f;

    int bn0 = n0 + r0, bn1 = n0 + r1;
    const int steps = K >> 6;
    u16x8 a0, a1, b0, b1;
    // prologue load (tile 0)
    a0 = *(const u16x8*)(A + (size_t)(m0 + r0) * K + schunk * 8);
    a1 = *(const u16x8*)(A + (size_t)(m0 + r1) * K + schunk * 8);
    b0 = b1 = (u16x8){0, 0, 0, 0, 0, 0, 0, 0};
    if (bn0 < N) b0 = *(const u16x8*)(B + (size_t)bn0 * K + schunk * 8);
    if (bn1 < N) b1 = *(const u16x8*)(B + (size_t)bn1 * K + schunk * 8);

    for (int s = 0; s < steps; ++s) {
        __syncthreads();
        *(u16x8*)(AsB + wb0) = a0;
        *(u16x8*)(AsB + wb1) = a1;
        *(u16x8*)(BsB + wb0) = b0;
        *(u16x8*)(BsB + wb1) = b1;
        __syncthreads();
        if (s + 1 < steps) {
            int k0 = (s + 1) << 6;
            a0 = *(const u16x8*)(A + (size_t)(m0 + r0) * K + k0 + schunk * 8);
            a1 = *(const u16x8*)(A + (size_t)(m0 + r1) * K + k0 + schunk * 8);
            if (bn0 < N) b0 = *(const u16x8*)(B + (size_t)bn0 * K + k0 + schunk * 8);
            if (bn1 < N) b1 = *(const u16x8*)(B + (size_t)bn1 * K + k0 + schunk * 8);
        }
#pragma unroll
        for (int ks = 0; ks < 2; ++ks) {
            int kb = ks * 64 + fg * 16;
            u16x8 af[2], bf[2];
#pragma unroll
            for (int mf = 0; mf < 2; ++mf) {
                int row = wr * 32 + mf * 16 + fr;
                af[mf] = *(const u16x8*)(AsB + row * 128 + (kb ^ ((row & 7) << 4)));
            }
#pragma unroll
            for (int nf = 0; nf < 2; ++nf) {
                int row = wc * 32 + nf * 16 + fr;
                bf[nf] = *(const u16x8*)(BsB + row * 128 + (kb ^ ((row & 7) << 4)));
            }
#pragma unroll
            for (int mf = 0; mf < 2; ++mf)
#pragma unroll
                for (int nf = 0; nf < 2; ++nf)
                    acc[mf][nf] = __builtin_amdgcn_mfma_f32_16x16x32_bf16(
                        __builtin_bit_cast(bf16x8, af[mf]),
                        __builtin_bit_cast(bf16x8, bf[nf]), acc[mf][nf], 0, 0, 0);
        }
    }

    if (mode == 1) {
        // fused: gelu -> silu + bspline -> augmented A2 row (bf16)
#pragma unroll
        for (int mf = 0; mf < 2; ++mf)
#pragma unroll
            for (int nf = 0; nf < 2; ++nf)
#pragma unroll
                for (int r = 0; r < 4; ++r) {
                    int row = m0 + wr * 32 + mf * 16 + fg * 4 + r;  // token
                    int col = n0 + wc * 32 + nf * 16 + fr;          // hid
                    if (col < N) {
                        float g = gelu_f(acc[mf][nf][r]);
                        unsigned short* rr = A2 + ((size_t)e * NTOK + row) * K2P;
                        rr[col] = f2bf(silu_f(g));
                        float bs[8]; bspline8(g, bs);
                        u16x8 pk;
#pragma unroll
                        for (int c = 0; c < 8; ++c) pk[c] = f2bf(bs[c]);
                        *(u16x8*)(rr + HID + col * 8) = pk;
                    }
                }
    } else {
        float* Ce = C + (size_t)e * sC;
#pragma unroll
        for (int mf = 0; mf < 2; ++mf)
#pragma unroll
            for (int nf = 0; nf < 2; ++nf)
#pragma unroll
                for (int r = 0; r < 4; ++r) {
                    int row = m0 + wr * 32 + mf * 16 + fg * 4 + r;
                    int col = n0 + wc * 32 + nf * 16 + fr;
                    if (col < N) Ce[(size_t)row * ldc + col] = acc[mf][nf][r];
                }
    }
}

// ---- 5+6. combine experts + classifier KAN ---------------------------------
__global__ __launch_bounds__(256) void combcls_kernel(const float* __restrict__ y,
                                                      const float* __restrict__ cw,
                                                      const float* __restrict__ lnw,
                                                      const float* __restrict__ lnb,
                                                      const float* __restrict__ cbw,
                                                      const float* __restrict__ csw,
                                                      const float* __restrict__ csc,
                                                      float* __restrict__ lblk) {
    int n = blockIdx.x, i = threadIdx.x;
    float v = 0.f;
#pragma unroll
    for (int e = 0; e < NE; ++e)
        v += cw[e * NTOK + n] * y[((size_t)(e * NTOK + n)) * CF + i];
    float s1 = v, s2 = v * v;
#pragma unroll
    for (int off = 32; off > 0; off >>= 1) {
        s1 += __shfl_xor(s1, off);
        s2 += __shfl_xor(s2, off);
    }
    __shared__ float rA[4], rB[4], rP0[4], rP1[4];
    int lane = i & 63, wid = i >> 6;
    if (lane == 0) { rA[wid] = s1; rB[wid] = s2; }
    __syncthreads();
    float tot1 = rA[0] + rA[1] + rA[2] + rA[3];
    float tot2 = rB[0] + rB[1] + rB[2] + rB[3];
    float mu = tot1 * (1.0f / CF);
    float var = tot2 * (1.0f / CF) - mu * mu;
    float rs = rsqrtf(var + 1e-5f);
    float xh = (v - mu) * rs * lnw[i] + lnb[i];
    float si = silu_f(xh);
    float bs[8]; bspline8(xh, bs);
    float p0 = si * cbw[i], p1 = si * cbw[CF + i];
    float sp0 = 0.f, sp1 = 0.f;
#pragma unroll
    for (int c = 0; c < 8; ++c) {
        sp0 += bs[c] * csw[(size_t)i * 8 + c];
        sp1 += bs[c] * csw[(size_t)(CF + i) * 8 + c];
    }
    p0 += sp0 * csc[i];
    p1 += sp1 * csc[CF + i];
#pragma unroll
    for (int off = 32; off > 0; off >>= 1) {
        p0 += __shfl_xor(p0, off);
        p1 += __shfl_xor(p1, off);
    }
    if (lane == 0) { rP0[wid] = p0; rP1[wid] = p1; }
    __syncthreads();
    if (i == 0) {
        lblk[n * 2 + 0] = rP0[0] + rP0[1] + rP0[2] + rP0[3];
        lblk[n * 2 + 1] = rP1[0] + rP1[1] + rP1[2] + rP1[3];
    }
}

// ---- 7. per-batch confidence softmax + weighted sum ------------------------
__global__ __launch_bounds__(64) void final_kernel(const float* __restrict__ conf,
                                                   const float* __restrict__ lblk,
                                                   float* __restrict__ out) {
    int b = blockIdx.x, p = threadIdx.x;
    float cf = conf[b * 64 + p];
    float mx = cf;
#pragma unroll
    for (int off = 32; off > 0; off >>= 1) mx = fmaxf(mx, __shfl_xor(mx, off));
    float ev = expf(cf - mx);
    float s = ev;
#pragma unroll
    for (int off = 32; off > 0; off >>= 1) s += __shfl_xor(s, off);
    float w = ev / s;
    float l0 = w * lblk[(b * 64 + p) * 2 + 0];
    float l1 = w * lblk[(b * 64 + p) * 2 + 1];
#pragma unroll
    for (int off = 32; off > 0; off >>= 1) {
        l0 += __shfl_xor(l0, off);
        l1 += __shfl_xor(l1, off);
    }
    if (p == 0) { out[b * 2 + 0] = l0; out[b * 2 + 1] = l1; }
}

extern "C" void kernel_launch(void* const* d_in, const int* in_sizes, int n_in,
                              void* d_out, int out_size, void* d_ws, size_t ws_size,
                              hipStream_t stream) {
    const float* fpn      = (const float*)d_in[0];
    const float* seg      = (const float*)d_in[1];
    const float* ln_r_w   = (const float*)d_in[2];
    const float* ln_r_b   = (const float*)d_in[3];
    const float* ln_h_w   = (const float*)d_in[4];
    const float* ln_h_b   = (const float*)d_in[5];
    const float* router_w = (const float*)d_in[6];
    const float* router_b = (const float*)d_in[7];
    const float* bw1      = (const float*)d_in[8];
    const float* sw1      = (const float*)d_in[9];
    const float* sc1      = (const float*)d_in[10];
    const float* bw2      = (const float*)d_in[11];
    const float* sw2      = (const float*)d_in[12];
    const float* sc2      = (const float*)d_in[13];
    const float* cls_bw   = (const float*)d_in[14];
    const float* cls_sw   = (const float*)d_in[15];
    const float* cls_sc   = (const float*)d_in[16];

    float* ws = (float*)d_ws;
    float* vec    = ws;                    // 131072
    float* scores = vec + 131072;          // 4096
    float* cw     = scores + 4096;         // 4096
    float* conf   = cw + 4096;             // 512
    float* lblk   = conf + 512;            // 1024
    float* yall   = lblk + 1024;           // 8*512*256 = 1048576
    unsigned short* A1b = (unsigned short*)(yall + 1048576);   // 512*2304
    unsigned short* W1b = A1b + (size_t)NTOK * K1;             // 8*170*2304
    unsigned short* A2b = W1b + (size_t)NE * HID * K1;         // 8*512*1536
    unsigned short* W2b = A2b + (size_t)NE * NTOK * K2P;       // 8*256*1536

    // front end: pool (2048 blocks) + W1 build (1360) + W2 build (2048)
    mega_front_kernel<<<dim3(2048 + NE * HID + 2048), dim3(256), 0, stream>>>(
        fpn, seg, bw1, sw1, sc1, bw2, sw2, sc2, vec, W1b, W2b);
    ln_score_a1_kernel<<<dim3(NTOK), dim3(256), 0, stream>>>(vec, ln_r_w, ln_r_b, router_w,
                                                             router_b, scores, A1b);
    topk_kernel<<<dim3(1), dim3(512), 0, stream>>>(scores, cw, conf);
    // layer1 GEMM, epilogue emits augmented A2 directly
    gemm_mfma_kernel<<<dim3(3, 8, NE), dim3(256), 0, stream>>>(
        A1b, W1b, nullptr, A2b, HID, K1, 0L, (long)HID * K1, 0L, 0, 1);
    // layer2 GEMM -> yall
    gemm_mfma_kernel<<<dim3(4, 8, NE), dim3(256), 0, stream>>>(
        A2b, W2b, yall, nullptr, CF, K2P, (long)NTOK * K2P, (long)CF * K2P,
        (long)NTOK * CF, CF, 0);
    combcls_kernel<<<dim3(NTOK), dim3(256), 0, stream>>>(yall, cw, ln_h_w, ln_h_b, cls_bw,
                                                         cls_sw, cls_sc, lblk);
    final_kernel<<<dim3(8), dim3(64), 0, stream>>>(conf, lblk, (float*)d_out);
}